// Round 13
// baseline (66.080 us; speedup 1.0000x reference)
//
#include <hip/hip_runtime.h>
#include <cstdint>
#include <cstddef>

#define B 128
#define P 8732
#define NC 21
#define O 16
#define THRESH 0.5f
#define QPI 2183   // quads per image = P/4
#define NBX 9      // pass2 blocks per image
#define NPART (B * NBX)
#define NB1 8      // pass1 blocks per image

typedef unsigned long long u64;
typedef unsigned int u32;
typedef unsigned char u8;

__device__ __forceinline__ float iou_pt(float a0, float a1, float a2, float a3,
                                        float b0, float b1, float b2, float b3) {
    float ltx = fmaxf(a0, b0), lty = fmaxf(a1, b1);
    float rbx = fminf(a2, b2), rby = fminf(a3, b3);
    float wx = fmaxf(rbx - ltx, 0.0f), wy = fmaxf(rby - lty, 0.0f);
    float inter = wx * wy;
    float aa = (a2 - a0) * (a3 - a1);
    float ab = (b2 - b0) * (b3 - b1);
    return inter / (aa + ab - inter);
}

// Pass 1: per-object best-prior partial max (plain stores) AND per-prior
// packed best-truth byte: idx | (ov>=THRESH ? 0x80 : 0).
__global__ void __launch_bounds__(256) k_pass1(const float* __restrict__ gt,
                                               const float* __restrict__ priors,
                                               u64* __restrict__ bk,
                                               u8* __restrict__ bidx) {
    const int b = blockIdx.y;
    __shared__ float s_gt[O * 4];
    __shared__ u64 s_wk[4][O];
    const int tid = threadIdx.x;
    const int wave = tid >> 6, lane = tid & 63;
    if (tid < O * 4) {
        int o = tid >> 2, c = tid & 3;
        s_gt[tid] = gt[(b * O + o) * 5 + c];
    }
    __syncthreads();

    u64 lk[O];
#pragma unroll
    for (int o = 0; o < O; o++) lk[o] = 0ull;

    for (int p = blockIdx.x * 256 + tid; p < P; p += NB1 * 256) {
        float4 pr = reinterpret_cast<const float4*>(priors)[p];
        float b0 = pr.x - pr.z * 0.5f, b1 = pr.y - pr.w * 0.5f;
        float b2 = pr.x + pr.z * 0.5f, b3 = pr.y + pr.w * 0.5f;
        float bov = -1.0f; int bo = 0;
#pragma unroll
        for (int o = 0; o < O; o++) {
            float v = iou_pt(s_gt[o * 4 + 0], s_gt[o * 4 + 1], s_gt[o * 4 + 2], s_gt[o * 4 + 3],
                             b0, b1, b2, b3);
            u64 key = ((u64)__float_as_uint(v) << 32) | (u64)(0xFFFFFFFFu - (u32)p);
            lk[o] = (key > lk[o]) ? key : lk[o];
            if (v > bov) { bov = v; bo = o; }   // first occurrence on tie
        }
        bidx[(size_t)b * P + p] = (u8)(bo | ((bov >= THRESH) ? 0x80 : 0));
    }

#pragma unroll
    for (int o = 0; o < O; o++) {
        u64 k = lk[o];
#pragma unroll
        for (int off = 32; off > 0; off >>= 1) {
            u64 other = (u64)__shfl_xor((long long)k, off, 64);
            k = (other > k) ? other : k;
        }
        if (lane == 0) s_wk[wave][o] = k;
    }
    __syncthreads();
    if (tid < O) {
        u64 k = s_wk[0][tid];
#pragma unroll
        for (int w = 1; w < 4; w++) { u64 v = s_wk[w][tid]; k = (v > k) ? v : k; }
        bk[((size_t)b * O + tid) * NB1 + blockIdx.x] = k;
    }
}

// Merge: reduce the 8 partial keys per (b,o) and PATCH the override straight
// into bidx (bidx[b][p*] = o|0x80). One thread per image, o ascending in
// program order => exact last-wins. Removes the 16-iter override loop (and
// the bk reduce) from pass2's per-prior hot path entirely.
__global__ void __launch_bounds__(128) k_merge(const u64* __restrict__ bk,
                                               u8* __restrict__ bidx) {
    const int b = threadIdx.x;
    u64 kk[O];
#pragma unroll
    for (int o = 0; o < O; o++) {
        u64 k = bk[((size_t)b * O + o) * NB1];
#pragma unroll
        for (int i = 1; i < NB1; i++) {
            u64 v = bk[((size_t)b * O + o) * NB1 + i];
            k = (v > k) ? v : k;
        }
        kk[o] = k;
    }
#pragma unroll
    for (int o = 0; o < O; o++) {
        int p = (int)(0xFFFFFFFFu - (u32)(kk[o] & 0xFFFFFFFFull));
        bidx[(size_t)b * P + p] = (u8)(o | 0x80);
    }
}

// Pass 2: 4 priors/thread, 21 float4 register loads; match = one packed u32
// read (override pre-patched by k_merge). Gather + priors + encode only on
// the (rare) matched path. Plain partial stores, no atomics.
__global__ void __launch_bounds__(256) k_pass2(const float* __restrict__ gt,
                                               const float* __restrict__ priors,
                                               const u8* __restrict__ bidx,
                                               const float* __restrict__ loc_preds,
                                               const float* __restrict__ scores,
                                               float* __restrict__ mine,
                                               double* __restrict__ pl,
                                               double* __restrict__ pc,
                                               int* __restrict__ pn) {
    const int b = blockIdx.y;
    __shared__ float s_gt[O * 5];
    const int tid = threadIdx.x;
    if (tid < O * 5) s_gt[tid] = gt[b * O * 5 + tid];
    __syncthreads();

    const int gq = blockIdx.x * 256 + tid;  // quad index within image
    float l_loc = 0.f, l_ce = 0.f;
    int l_np = 0;

    if (gq < QPI) {
        const int p0 = gq * 4;
        float fs[84];
        const float4* s4 = reinterpret_cast<const float4*>(scores)
                           + (size_t)b * (size_t)(P * NC / 4) + (size_t)21 * gq;
#pragma unroll
        for (int i = 0; i < 21; i++) {
            float4 v = s4[i];
            fs[4 * i + 0] = v.x; fs[4 * i + 1] = v.y;
            fs[4 * i + 2] = v.z; fs[4 * i + 3] = v.w;
        }
        const u32 mw = *reinterpret_cast<const u32*>(bidx + (size_t)b * P + p0);

        float mine_v[4];

#pragma unroll
        for (int j = 0; j < 4; j++) {
            const int p = p0 + j;

            int e = (int)((mw >> (8 * j)) & 0xFFu);
            int best_idx = e & 0x3F;
            bool matched = (e & 0x80) != 0;   // matched <=> positive (labels >= 1)
            int cls = matched ? (int)s_gt[best_idx * 5 + 4] : 0;

            float mx = fs[21 * j];
#pragma unroll
            for (int c = 1; c < NC; c++) mx = fmaxf(mx, fs[21 * j + c]);
            float se = 0.0f;
#pragma unroll
            for (int c = 0; c < NC; c++) se += __expf(fs[21 * j + c] - mx);
            float lse = mx + __logf(se);

            if (!matched) {
                // cls == 0 -> gather is fs[0], free
                mine_v[j] = lse - fs[21 * j];
            } else {
                mine_v[j] = 0.0f;
                float g = fs[21 * j + 1];
#pragma unroll
                for (int c = 2; c < NC; c++) g = (c == cls) ? fs[21 * j + c] : g;
                float ce = lse - g;
                l_np++;
                l_ce += ce;
                float4 pr = reinterpret_cast<const float4*>(priors)[p];   // pos-path only
                float m0 = s_gt[best_idx * 5 + 0], m1 = s_gt[best_idx * 5 + 1];
                float m2 = s_gt[best_idx * 5 + 2], m3 = s_gt[best_idx * 5 + 3];
                float tx = ((m0 + m2) * 0.5f - pr.x) / (0.1f * pr.z);
                float ty = ((m1 + m3) * 0.5f - pr.y) / (0.1f * pr.w);
                float tw = __logf((m2 - m0) / pr.z) * 5.0f;
                float th = __logf((m3 - m1) / pr.w) * 5.0f;
                float4 lp = reinterpret_cast<const float4*>(loc_preds)[(size_t)b * P + p];
                float d0 = fabsf(lp.x - tx), d1 = fabsf(lp.y - ty);
                float d2 = fabsf(lp.z - tw), d3 = fabsf(lp.w - th);
                float s0 = d0 < 1.0f ? 0.5f * d0 * d0 : d0 - 0.5f;
                float s1 = d1 < 1.0f ? 0.5f * d1 * d1 : d1 - 0.5f;
                float s2 = d2 < 1.0f ? 0.5f * d2 * d2 : d2 - 0.5f;
                float s3 = d3 < 1.0f ? 0.5f * d3 * d3 : d3 - 0.5f;
                l_loc += (s0 + s1) + (s2 + s3);
            }
        }
        float4 mv = make_float4(mine_v[0], mine_v[1], mine_v[2], mine_v[3]);
        reinterpret_cast<float4*>(mine)[((size_t)b * P + p0) >> 2] = mv;
    }

    // wave shuffle reductions (float partials -> double at wave leader)
    const int lane = tid & 63;
    const int wave = tid >> 6;
#pragma unroll
    for (int off = 32; off > 0; off >>= 1) {
        l_loc += __shfl_xor(l_loc, off, 64);
        l_ce  += __shfl_xor(l_ce, off, 64);
        l_np  += __shfl_xor(l_np, off, 64);
    }
    __shared__ double s_loc[4], s_ce[4];
    __shared__ int s_np[4];
    if (lane == 0) { s_loc[wave] = (double)l_loc; s_ce[wave] = (double)l_ce; s_np[wave] = l_np; }
    __syncthreads();
    if (tid == 0) {
        int q = b * NBX + blockIdx.x;
        pl[q] = (s_loc[0] + s_loc[1]) + (s_loc[2] + s_loc[3]);
        pc[q] = (s_ce[0] + s_ce[1]) + (s_ce[2] + s_ce[3]);
        pn[q] = s_np[0] + s_np[1] + s_np[2] + s_np[3];
    }
}

// Hard-negative top-k sum; self-computes total_pos; plain stores; no atomics.
__global__ void __launch_bounds__(1024) k_hardneg(const float* __restrict__ mine,
                                                  const int* __restrict__ pn,
                                                  double* __restrict__ pneg) {
    const int b = blockIdx.x;
    const int tid = threadIdx.x;
    const int lane = tid & 63, wave = tid >> 6;
    __shared__ float s_mine[P];
    __shared__ u32 s_hist[256];
    __shared__ u32 s_sel[2];
    __shared__ double s_red[16];
    __shared__ int s_ti[16];
    __shared__ int s_npx[NBX];
    __shared__ int s_k;

    {
        int t = 0;
        for (int i = tid; i < NPART; i += 1024) t += pn[i];
#pragma unroll
        for (int off = 32; off > 0; off >>= 1) t += __shfl_xor(t, off, 64);
        if (lane == 0) s_ti[wave] = t;
    }
    if (tid < NBX) s_npx[tid] = pn[b * NBX + tid];
    __syncthreads();
    if (tid == 0) {
        int tp = 0;
#pragma unroll
        for (int w = 0; w < 16; w++) tp += s_ti[w];
        int np = 0;
#pragma unroll
        for (int x = 0; x < NBX; x++) np += s_npx[x];
        int k = 3 * np;
        int cap = P - tp - 1;
        if (cap < k) k = cap;
        s_k = k;
    }
    __syncthreads();
    const int k = s_k;

    if (k <= 0) {
        if (tid == 0) pneg[b] = 0.0;
        return;
    }

    for (int i = tid; i < P; i += 1024) s_mine[i] = mine[(size_t)b * P + i];
    if (tid == 0) { s_sel[0] = 0u; s_sel[1] = (u32)k; }
    __syncthreads();

    for (int shift = 24; shift >= 0; shift -= 8) {
        if (tid < 256) s_hist[tid] = 0u;
        __syncthreads();
        u32 prefix = s_sel[0];
        u32 kr = s_sel[1];
        u32 himask = (shift == 24) ? 0u : (0xFFFFFFFFu << (shift + 8));
        for (int i = tid; i < P; i += 1024) {
            u32 v = __float_as_uint(s_mine[i]);
            if ((v & himask) == prefix) atomicAdd(&s_hist[(v >> shift) & 255u], 1u);
        }
        __syncthreads();
        if (tid < 64) {
            const int L = tid;
            const int btop = 255 - 4 * L;
            u32 h0 = s_hist[btop], h1 = s_hist[btop - 1], h2 = s_hist[btop - 2], h3 = s_hist[btop - 3];
            u32 g4 = h0 + h1 + h2 + h3;
            u32 x = g4;
#pragma unroll
            for (int off = 1; off < 64; off <<= 1) {
                u32 v = __shfl_up(x, off, 64);
                if (L >= off) x += v;
            }
            u32 excl = x - g4;
            if (excl < kr && excl + g4 >= kr) {
                u32 c = excl; int chosen = btop; u32 kloc = kr;
                u32 nc;
                nc = c + h0; if (c < kr && nc >= kr) { chosen = btop;     kloc = kr - c; } c = nc;
                nc = c + h1; if (c < kr && nc >= kr) { chosen = btop - 1; kloc = kr - c; } c = nc;
                nc = c + h2; if (c < kr && nc >= kr) { chosen = btop - 2; kloc = kr - c; } c = nc;
                nc = c + h3; if (c < kr && nc >= kr) { chosen = btop - 3; kloc = kr - c; } c = nc;
                s_sel[0] = prefix | ((u32)chosen << shift);
                s_sel[1] = kloc;
            }
        }
        __syncthreads();
    }

    u32 tbits = s_sel[0];
    u32 kr = s_sel[1];
    float T = __uint_as_float(tbits);

    double sd = 0.0;
    for (int i = tid; i < P; i += 1024) {
        u32 v = __float_as_uint(s_mine[i]);
        if (v > tbits) sd += (double)s_mine[i];
    }
#pragma unroll
    for (int off = 32; off > 0; off >>= 1) sd += __shfl_xor(sd, off, 64);
    if (lane == 0) s_red[wave] = sd;
    __syncthreads();
    if (tid == 0) {
        double tt = 0.0;
#pragma unroll
        for (int w = 0; w < 16; w++) tt += s_red[w];
        pneg[b] = tt + (double)kr * (double)T;
    }
}

// Final: sum all partials, write both outputs.
__global__ void __launch_bounds__(1024) k_fin(const double* __restrict__ pl,
                                              const double* __restrict__ pc,
                                              const int* __restrict__ pn,
                                              const double* __restrict__ pneg,
                                              float* __restrict__ out) {
    const int tid = threadIdx.x;
    const int lane = tid & 63, wave = tid >> 6;
    __shared__ double s_l[16], s_c[16], s_g[16];
    __shared__ int s_t[16];

    double tl = 0.0, tc = 0.0, tg = 0.0;
    int tn = 0;
    for (int i = tid; i < NPART; i += 1024) { tl += pl[i]; tc += pc[i]; tn += pn[i]; }
    if (tid < B) tg = pneg[tid];
#pragma unroll
    for (int off = 32; off > 0; off >>= 1) {
        tl += __shfl_xor(tl, off, 64);
        tc += __shfl_xor(tc, off, 64);
        tg += __shfl_xor(tg, off, 64);
        tn += __shfl_xor(tn, off, 64);
    }
    if (lane == 0) { s_l[wave] = tl; s_c[wave] = tc; s_g[wave] = tg; s_t[wave] = tn; }
    __syncthreads();
    if (tid == 0) {
        double al = 0.0, ac = 0.0, ag = 0.0;
        int an = 0;
#pragma unroll
        for (int w = 0; w < 16; w++) { al += s_l[w]; ac += s_c[w]; ag += s_g[w]; an += s_t[w]; }
        double n = (double)an;
        out[0] = (float)(al / n);
        out[1] = (float)((ac + ag) / n);
    }
}

extern "C" void kernel_launch(void* const* d_in, const int* in_sizes, int n_in,
                              void* d_out, int out_size, void* d_ws, size_t ws_size,
                              hipStream_t stream) {
    const float* loc_preds = (const float*)d_in[0];
    const float* scores    = (const float*)d_in[1];
    const float* gt        = (const float*)d_in[2];
    const float* priors    = (const float*)d_in[3];

    char* ws = (char*)d_ws;
    u64* bk      = (u64*)ws;                  // [0, 131072)        B*O*NB1 u64
    double* pl   = (double*)(ws + 131072);    // [131072, 140288)   NPART dbl
    double* pc   = (double*)(ws + 140288);    // [140288, 149504)
    int* pn      = (int*)(ws + 149504);       // [149504, 154112)
    double* pneg = (double*)(ws + 154112);    // [154112, 155136)
    u8* bidx     = (u8*)(ws + 155136);        // [155136, 1272832)  B*P u8
    float* mine  = (float*)(ws + 1272832);    // B*P*4 (16B-aligned)

    // no memset needed: every ws slot consumed is plainly overwritten each call

    k_pass1<<<dim3(NB1, B), dim3(256), 0, stream>>>(gt, priors, bk, bidx);
    k_merge<<<dim3(1), dim3(128), 0, stream>>>(bk, bidx);
    k_pass2<<<dim3(NBX, B), dim3(256), 0, stream>>>(
        gt, priors, bidx, loc_preds, scores, mine, pl, pc, pn);
    k_hardneg<<<dim3(B), dim3(1024), 0, stream>>>(mine, pn, pneg);
    k_fin<<<dim3(1), dim3(1024), 0, stream>>>(pl, pc, pn, pneg, (float*)d_out);
}